// Round 1
// baseline (189.428 us; speedup 1.0000x reference)
//
#include <hip/hip_runtime.h>
#include <math.h>

// Problem constants (reference: B=16, C=2, H=512, W=512; gt in {0,1})
constexpr int BATCH = 16;
constexpr int H = 512;
constexpr int W = 512;
constexpr float INV_N = 1.0f / (float)(16 * 512 * 512);  // mean over B*H*W

// One block per (batch, row): 512 threads, one per column.
// Pass 1 (vertical EDT) via outward first-hit scan on gt (coalesced).
// Pass 2 (horizontal exact min-plus) on the d1 row staged in LDS with
// the exact early-exit t*t >= best.
// Epilogue: weighted sum reduction -> one atomicAdd per block.
__global__ __launch_bounds__(512) void boundary_loss_kernel(
    const float* __restrict__ probs,  // [B, 2, H, W]
    const int* __restrict__ gt,       // [B, 1, H, W]
    float* __restrict__ out)          // [1]
{
    const int row = blockIdx.x;       // 0 .. B*H-1
    const int b = row / H;
    const int i = row % H;
    const int j = threadIdx.x;        // 0 .. W-1

    const int* col = gt + (size_t)b * H * W + j;

    // --- vertical nearest-foreground scan (exact, early exit) ---
    int tu = -1;  // distance to nearest fg at-or-above
    for (int t = 0; t <= i; ++t) {
        if (col[(i - t) * W] != 0) { tu = t; break; }
    }
    int td = -1;  // distance to nearest fg at-or-below
    for (int t = 0; t < H - i; ++t) {
        if (col[(i + t) * W] != 0) { td = t; break; }
    }
    // Reference sentinels for fg-free half-columns:
    // f = -BIG (BIG = 2*(H+W) = 2048)  -> (i + 2048)^2
    // b = BIG + H = 2560               -> (2560 - i)^2
    int du = (tu >= 0) ? tu * tu : (i + 2048) * (i + 2048);
    int dd = (td >= 0) ? td * td : (2560 - i) * (2560 - i);
    int d1 = min(du, dd);

    __shared__ int d1row[W];
    d1row[j] = d1;
    __syncthreads();

    // --- horizontal exact min-plus with early exit ---
    // Candidates at offset t contribute d1 + t^2 >= t^2, so once
    // t^2 >= best no farther column can improve: exact break.
    int best = d1;
    for (int t = 1; t < W; ++t) {
        int tt = t * t;
        if (tt >= best) break;
        if (j - t >= 0) best = min(best, d1row[j - t] + tt);
        if (j + t < W)  best = min(best, d1row[j + t] + tt);
    }

    float dist = sqrtf((float)best);
    float v = probs[(size_t)b * 2 * H * W + (size_t)i * W + j] * dist;

    // --- block reduction: wave shuffle (64 lanes) then LDS ---
    for (int off = 32; off > 0; off >>= 1)
        v += __shfl_down(v, off, 64);
    __shared__ float wsum[8];
    const int lane = j & 63;
    const int wid = j >> 6;
    if (lane == 0) wsum[wid] = v;
    __syncthreads();
    if (j == 0) {
        float s = 0.0f;
        #pragma unroll
        for (int w = 0; w < 8; ++w) s += wsum[w];
        atomicAdd(out, s * INV_N);
    }
}

extern "C" void kernel_launch(void* const* d_in, const int* in_sizes, int n_in,
                              void* d_out, int out_size, void* d_ws, size_t ws_size,
                              hipStream_t stream) {
    const float* probs = (const float*)d_in[0];
    const int* gt = (const int*)d_in[1];
    float* out = (float*)d_out;

    // d_out is re-poisoned (0xAA) before every timed replay: zero it first.
    hipMemsetAsync(out, 0, (size_t)out_size * sizeof(float), stream);

    dim3 grid(BATCH * H);
    dim3 block(W);
    boundary_loss_kernel<<<grid, block, 0, stream>>>(probs, gt, out);
}